// Round 6
// baseline (62.390 us; speedup 1.0000x reference)
//
#include <hip/hip_runtime.h>

// Problem constants (from reference)
#define TOK_CODE_START 256
#define TOK_CODE_END   257
#define TOK_MEM        258
#define ADDR_KEY       206
#define MEM_STORE      455

constexpr int Bb = 16;
constexpr int Ss = 8192;
constexpr int DM = 512;
constexpr int CHUNK = 64;            // positions per gather block
constexpr int NCH = Ss / CHUNK;      // 128 chunks per row
constexpr int QPP = DM / 4;          // 128 float4 quads per position

typedef float f32x4 __attribute__((ext_vector_type(4)));

// ---------------------------------------------------------------------------
// Kernel 1 (tiny): per-row chunk summaries + exclusive prefix scan.
// One block per row, 128 threads; thread t reduces chunk t's 64 tokens to
// {last CODE_START idx, first CODE_END idx}, then a 2-wave exclusive scan
// produces, per chunk: P = latest START strictly before the chunk (-1 none),
// E = earliest END strictly before the chunk (Ss none). 16 KB output.
// ---------------------------------------------------------------------------
__global__ __launch_bounds__(128) void vm_summary_kernel(
    const int* __restrict__ tok,
    int2* __restrict__ summ)
{
    const int b = blockIdx.x;
    const int t = threadIdx.x;           // chunk id 0..127
    const int lane = t & 63;
    const int w = t >> 6;                // 0 or 1
    const int* chunk = tok + b * Ss + t * CHUNK;

    int maxStart = -1, minEnd = Ss;
    #pragma unroll
    for (int j = 0; j < 16; ++j) {
        int4 v = reinterpret_cast<const int4*>(chunk)[j];
        int i0 = t * CHUNK + j * 4;
        if (v.x == TOK_CODE_START) maxStart = i0;
        if (v.y == TOK_CODE_START) maxStart = i0 + 1;
        if (v.z == TOK_CODE_START) maxStart = i0 + 2;
        if (v.w == TOK_CODE_START) maxStart = i0 + 3;     // ascending -> max
        if (v.x == TOK_CODE_END && minEnd == Ss) minEnd = i0;
        if (v.y == TOK_CODE_END && minEnd == Ss) minEnd = i0 + 1;
        if (v.z == TOK_CODE_END && minEnd == Ss) minEnd = i0 + 2;
        if (v.w == TOK_CODE_END && minEnd == Ss) minEnd = i0 + 3;
    }

    // inclusive wave scans (max of maxStart, min of minEnd)
    int ms = maxStart, me = minEnd;
    #pragma unroll
    for (int off = 1; off < 64; off <<= 1) {
        int u = __shfl_up(ms, off);
        int v = __shfl_up(me, off);
        if (lane >= off) { if (u > ms) ms = u; if (v < me) me = v; }
    }
    __shared__ int cMs, cMe;             // wave-0 totals (carry into wave 1)
    if (w == 0 && lane == 63) { cMs = ms; cMe = me; }
    __syncthreads();
    // exclusive = shift by one, identity at lane 0, carry for wave 1
    int pms = __shfl_up(ms, 1);
    int pme = __shfl_up(me, 1);
    if (lane == 0) { pms = -1; pme = Ss; }
    if (w == 1) { if (cMs > pms) pms = cMs; if (cMe < pme) pme = cMe; }
    summ[b * NCH + t] = make_int2(pms, pme);
}

// ---------------------------------------------------------------------------
// Kernel 2: gather + mask + stream. Block bk owns row b=bk>>7, chunk c=bk&127.
// Wave 0 finishes the scan for its own 64 positions (coalesced 64-token load
// + chunk-prefix pair + 6 shuffle steps) -> packed mask words in LDS:
//   bits[0..8]=token  bit9=valid  bit10=mem_flag  bits[11..]=addr
// All waves then stream: L2-resident embed gather + mask + NONTEMPORAL
// dwordx4 stores (keeps the 268 MB write stream out of L2, which is busy
// serving the embed gathers).
// ---------------------------------------------------------------------------
__global__ __launch_bounds__(256) void vm_gather_kernel(
    const int* __restrict__ tok,
    const f32x4* __restrict__ emb,
    const int2* __restrict__ summ,
    const int* __restrict__ mhe_p,
    f32x4* __restrict__ out)
{
    const int bk = blockIdx.x;            // 0..2047
    const int b  = bk >> 7;
    const int c  = bk & 127;
    const int t  = threadIdx.x;
    const int lane = t & 63;
    const int s0 = c * CHUNK;

    __shared__ unsigned int smask[CHUNK];

    if (t < 64) {
        const int idx = s0 + lane;
        int tv = tok[b * Ss + idx];
        int2 pe = summ[bk];               // == summ[b*NCH + c]
        int st = (tv == TOK_CODE_START) ? idx : -1;
        int en = (tv == TOK_CODE_END) ? idx : Ss;
        #pragma unroll
        for (int off = 1; off < 64; off <<= 1) {
            int u = __shfl_up(st, off);
            int v = __shfl_up(en, off);
            if (lane >= off) { if (u > st) st = u; if (v < en) en = v; }
        }
        int cs = max(pe.x, st);           // latest START at-or-before idx
        int fe = min(pe.y, en);           // earliest END at-or-before idx (Ss if none)
        int addr = idx - cs - 1;
        bool valid = (cs >= 0) && (fe > idx) && (tv < 256) && (addr >= 0);
        bool memf  = (tv == TOK_MEM) && (idx < mhe_p[0]);
        unsigned int wd = (unsigned int)tv;              // bits 0..8
        if (valid) wd |= (1u << 9) | ((unsigned int)addr << 11);
        if (memf)  wd |= (1u << 10);
        smask[lane] = wd;
    }
    __syncthreads();

    const int outBase = bk * (CHUNK * QPP);              // bk * 8192
    #pragma unroll 8
    for (int i = 0; i < 32; ++i) {
        int q = i * 256 + t;                             // 0..8191, coalesced
        int pos = q >> 7;                                // == 2i + (t>>7): wave-uniform
        int dq = q & 127;
        // pos is wave-uniform -> hoist the packed word to an SGPR so the
        // mask test becomes a scalar branch (no exec-mask work in skip path)
        unsigned int pw = (unsigned int)
            __builtin_amdgcn_readfirstlane((int)smask[pos]);
        int tk = (int)(pw & 511u);
        f32x4 v = emb[tk * QPP + dq];
        unsigned int flags = pw >> 9;
        if (flags) {                                     // scalar branch, mostly false
            bool valid = (flags & 1u) != 0u;
            bool memf  = (flags & 2u) != 0u;
            int addr = (int)(flags >> 2);
            int p0 = ADDR_KEY      + (addr & 15);
            int p1 = ADDR_KEY + 16 + ((addr >> 4) & 15);
            int p2 = ADDR_KEY + 32 + ((addr >> 8) & 15);
            int d0 = dq << 2;
            #pragma unroll
            for (int j = 0; j < 4; ++j) {
                int d = d0 + j;
                if ((valid && (d == p0 || d == p1 || d == p2)) ||
                    (memf && d == MEM_STORE)) v[j] = 1.0f;
            }
        }
        __builtin_nontemporal_store(v, &out[outBase + q]);
    }
}

extern "C" void kernel_launch(void* const* d_in, const int* in_sizes, int n_in,
                              void* d_out, int out_size, void* d_ws, size_t ws_size,
                              hipStream_t stream) {
    const int* tok = (const int*)d_in[0];
    const f32x4* emb = (const f32x4*)d_in[1];
    const int* mhe = (const int*)d_in[2];
    int2* summ = (int2*)d_ws;             // 16*128*8 = 16 KiB
    f32x4* out = (f32x4*)d_out;

    vm_summary_kernel<<<Bb, 128, 0, stream>>>(tok, summ);
    vm_gather_kernel<<<Bb * NCH, 256, 0, stream>>>(tok, emb, summ, mhe, out);
}

// Round 7
// 62.307 us; speedup vs baseline: 1.0013x; 1.0013x over previous
//
#include <hip/hip_runtime.h>

// Problem constants (from reference)
#define TOK_CODE_START 256
#define TOK_CODE_END   257
#define TOK_MEM        258
#define ADDR_KEY       206
#define MEM_STORE      455

constexpr int Bb = 16;
constexpr int Ss = 8192;
constexpr int DM = 512;
constexpr int CHUNK = 64;            // positions per gather block
constexpr int NCH = Ss / CHUNK;      // 128 chunks per row
constexpr int QPP = DM / 4;          // 128 float4 quads per position

typedef float f32x4 __attribute__((ext_vector_type(4)));

// ---------------------------------------------------------------------------
// Kernel 1 (tiny): per-row chunk summaries + exclusive prefix scan.
// One block per row, 128 threads; thread t reduces chunk t's 64 tokens to
// {last CODE_START idx, first CODE_END idx}, then a 2-wave exclusive scan
// produces, per chunk: P = latest START strictly before the chunk (-1 none),
// E = earliest END strictly before the chunk (Ss none). 16 KB output.
// ---------------------------------------------------------------------------
__global__ __launch_bounds__(128) void vm_summary_kernel(
    const int* __restrict__ tok,
    int2* __restrict__ summ)
{
    const int b = blockIdx.x;
    const int t = threadIdx.x;           // chunk id 0..127
    const int lane = t & 63;
    const int w = t >> 6;                // 0 or 1
    const int* chunk = tok + b * Ss + t * CHUNK;

    int maxStart = -1, minEnd = Ss;
    #pragma unroll
    for (int j = 0; j < 16; ++j) {
        int4 v = reinterpret_cast<const int4*>(chunk)[j];
        int i0 = t * CHUNK + j * 4;
        if (v.x == TOK_CODE_START) maxStart = i0;
        if (v.y == TOK_CODE_START) maxStart = i0 + 1;
        if (v.z == TOK_CODE_START) maxStart = i0 + 2;
        if (v.w == TOK_CODE_START) maxStart = i0 + 3;     // ascending -> max
        if (v.x == TOK_CODE_END && minEnd == Ss) minEnd = i0;
        if (v.y == TOK_CODE_END && minEnd == Ss) minEnd = i0 + 1;
        if (v.z == TOK_CODE_END && minEnd == Ss) minEnd = i0 + 2;
        if (v.w == TOK_CODE_END && minEnd == Ss) minEnd = i0 + 3;
    }

    // inclusive wave scans (max of maxStart, min of minEnd)
    int ms = maxStart, me = minEnd;
    #pragma unroll
    for (int off = 1; off < 64; off <<= 1) {
        int u = __shfl_up(ms, off);
        int v = __shfl_up(me, off);
        if (lane >= off) { if (u > ms) ms = u; if (v < me) me = v; }
    }
    __shared__ int cMs, cMe;             // wave-0 totals (carry into wave 1)
    if (w == 0 && lane == 63) { cMs = ms; cMe = me; }
    __syncthreads();
    // exclusive = shift by one, identity at lane 0, carry for wave 1
    int pms = __shfl_up(ms, 1);
    int pme = __shfl_up(me, 1);
    if (lane == 0) { pms = -1; pme = Ss; }
    if (w == 1) { if (cMs > pms) pms = cMs; if (cMe < pme) pme = cMe; }
    summ[b * NCH + t] = make_int2(pms, pme);
}

// ---------------------------------------------------------------------------
// Kernel 2: gather + mask + stream. Block bk owns row b=bk>>7, chunk c=bk&127.
// Wave 0 finishes the scan for its own 64 positions (coalesced 64-token load
// + chunk-prefix pair + 6 shuffle steps) -> packed mask words in LDS:
//   bits[0..8]=token  bit9=valid  bit10=mem_flag  bits[11..]=addr
// All waves then stream: L2-resident embed gather + mask (vector predicate,
// NO scalar hoist — readfirstlane serialized the loop in R6) + NONTEMPORAL
// dwordx4 stores. Single change vs R5 (regular stores, 53.6 us): nt store.
// ---------------------------------------------------------------------------
__global__ __launch_bounds__(256) void vm_gather_kernel(
    const int* __restrict__ tok,
    const f32x4* __restrict__ emb,
    const int2* __restrict__ summ,
    const int* __restrict__ mhe_p,
    f32x4* __restrict__ out)
{
    const int bk = blockIdx.x;            // 0..2047
    const int b  = bk >> 7;
    const int c  = bk & 127;
    const int t  = threadIdx.x;
    const int lane = t & 63;
    const int s0 = c * CHUNK;

    __shared__ unsigned int smask[CHUNK];

    if (t < 64) {
        const int idx = s0 + lane;
        int tv = tok[b * Ss + idx];
        int2 pe = summ[bk];               // == summ[b*NCH + c]
        int st = (tv == TOK_CODE_START) ? idx : -1;
        int en = (tv == TOK_CODE_END) ? idx : Ss;
        #pragma unroll
        for (int off = 1; off < 64; off <<= 1) {
            int u = __shfl_up(st, off);
            int v = __shfl_up(en, off);
            if (lane >= off) { if (u > st) st = u; if (v < en) en = v; }
        }
        int cs = max(pe.x, st);           // latest START at-or-before idx
        int fe = min(pe.y, en);           // earliest END at-or-before idx (Ss if none)
        int addr = idx - cs - 1;
        bool valid = (cs >= 0) && (fe > idx) && (tv < 256) && (addr >= 0);
        bool memf  = (tv == TOK_MEM) && (idx < mhe_p[0]);
        unsigned int wd = (unsigned int)tv;              // bits 0..8
        if (valid) wd |= (1u << 9) | ((unsigned int)addr << 11);
        if (memf)  wd |= (1u << 10);
        smask[lane] = wd;
    }
    __syncthreads();

    const int outBase = bk * (CHUNK * QPP);              // bk * 8192
    #pragma unroll 8
    for (int i = 0; i < 32; ++i) {
        int q = i * 256 + t;                             // 0..8191, coalesced
        int pos = q >> 7;
        int dq = q & 127;
        unsigned int pw = smask[pos];
        int tk = (int)(pw & 511u);
        f32x4 v = emb[tk * QPP + dq];
        unsigned int flags = pw >> 9;
        if (flags) {                                     // wave-uniform, mostly false
            bool valid = (flags & 1u) != 0u;
            bool memf  = (flags & 2u) != 0u;
            int addr = (int)(flags >> 2);
            int p0 = ADDR_KEY      + (addr & 15);
            int p1 = ADDR_KEY + 16 + ((addr >> 4) & 15);
            int p2 = ADDR_KEY + 32 + ((addr >> 8) & 15);
            int d0 = dq << 2;
            #pragma unroll
            for (int j = 0; j < 4; ++j) {
                int d = d0 + j;
                if ((valid && (d == p0 || d == p1 || d == p2)) ||
                    (memf && d == MEM_STORE)) v[j] = 1.0f;
            }
        }
        __builtin_nontemporal_store(v, &out[outBase + q]);
    }
}

extern "C" void kernel_launch(void* const* d_in, const int* in_sizes, int n_in,
                              void* d_out, int out_size, void* d_ws, size_t ws_size,
                              hipStream_t stream) {
    const int* tok = (const int*)d_in[0];
    const f32x4* emb = (const f32x4*)d_in[1];
    const int* mhe = (const int*)d_in[2];
    int2* summ = (int2*)d_ws;             // 16*128*8 = 16 KiB
    f32x4* out = (f32x4*)d_out;

    vm_summary_kernel<<<Bb, 128, 0, stream>>>(tok, summ);
    vm_gather_kernel<<<Bb * NCH, 256, 0, stream>>>(tok, emb, summ, mhe, out);
}

// Round 8
// 51.869 us; speedup vs baseline: 1.2028x; 1.2012x over previous
//
#include <hip/hip_runtime.h>

// Problem constants (from reference)
#define TOK_CODE_START 256
#define TOK_CODE_END   257
#define TOK_MEM        258
#define ADDR_KEY       206
#define MEM_STORE      455

constexpr int Bb = 16;
constexpr int Ss = 8192;
constexpr int DM = 512;

typedef float f32x4 __attribute__((ext_vector_type(4)));

// ---------------------------------------------------------------------------
// Kernel 1: per-row scan. One block per batch row, 1024 threads (16 waves),
// 8 tokens per thread. Wave-level shuffle scan + one LDS round for the 16
// wave carries. Packs per (b,s):
//   bits[0..8]=token  bit9=valid  bit10=mem_flag  bits[11..]=addr
// into one u32 in d_ws.
// ---------------------------------------------------------------------------
__global__ __launch_bounds__(1024) void vm_scan_kernel(
    const int* __restrict__ tok,
    const int* __restrict__ mhe_p,
    unsigned int* __restrict__ ws)
{
    const int b = blockIdx.x;
    const int t = threadIdx.x;              // 0..1023
    const int lane = t & 63;
    const int wid = t >> 6;                 // 0..15
    const int mhe = mhe_p[0];
    const int* row = tok + b * Ss;
    const int base = t * 8;

    int toks[8];
    int4 v0 = reinterpret_cast<const int4*>(row + base)[0];
    int4 v1 = reinterpret_cast<const int4*>(row + base)[1];
    toks[0] = v0.x; toks[1] = v0.y; toks[2] = v0.z; toks[3] = v0.w;
    toks[4] = v1.x; toks[5] = v1.y; toks[6] = v1.z; toks[7] = v1.w;

    // per-thread chunk summaries
    int lmax = -1;      // max index of CODE_START in my 8 (-1 if none)
    int lend = Ss;      // first index of CODE_END in my 8 (Ss if none)
    #pragma unroll
    for (int k = 0; k < 8; ++k) {
        int idx = base + k;
        if (toks[k] == TOK_CODE_START) lmax = idx;             // idx increasing
        if (toks[k] == TOK_CODE_END && lend == Ss) lend = idx; // first
    }

    // wave inclusive max-scan of lmax (6 shuffle steps, no barriers)
    #pragma unroll
    for (int off = 1; off < 64; off <<= 1) {
        int u = __shfl_up(lmax, off);
        if (lane >= off && u > lmax) lmax = u;
    }
    // exclusive version for this thread
    int excl = __shfl_up(lmax, 1);
    if (lane == 0) excl = -1;

    // wave min-reduce of lend (all lanes get the wave min)
    #pragma unroll
    for (int off = 32; off > 0; off >>= 1) {
        int u = __shfl_xor(lend, off);
        if (u < lend) lend = u;
    }

    __shared__ int wmax[16];   // per-wave inclusive total (lane 63's value)
    __shared__ int wend[16];   // per-wave min first-end
    if (lane == 63) wmax[wid] = lmax;
    if (lane == 0)  wend[wid] = lend;
    __syncthreads();

    int carry = -1;
    #pragma unroll
    for (int j = 0; j < 16; ++j)
        if (j < wid && wmax[j] > carry) carry = wmax[j];
    int end_idx = Ss;
    #pragma unroll
    for (int j = 0; j < 16; ++j)
        if (wend[j] < end_idx) end_idx = wend[j];

    int run = (carry > excl) ? carry : excl;   // latest start strictly before my chunk

    unsigned int pk[8];
    #pragma unroll
    for (int k = 0; k < 8; ++k) {
        int idx = base + k;
        int tv = toks[k];
        if (tv == TOK_CODE_START) run = idx;   // inclusive cummax update
        int cs = run;
        int addr = idx - cs - 1;
        bool valid = (cs >= 0) && (idx < end_idx) && (tv < 256) && (addr >= 0);
        bool memf  = (tv == TOK_MEM) && (idx < mhe);
        unsigned int w = (unsigned int)tv;                       // bits 0..8
        if (valid) w |= (1u << 9) | ((unsigned int)addr << 11);
        if (memf)  w |= (1u << 10);
        pk[k] = w;
    }
    uint4* wr = reinterpret_cast<uint4*>(ws + b * Ss + base);
    wr[0] = make_uint4(pk[0], pk[1], pk[2], pk[3]);
    wr[1] = make_uint4(pk[4], pk[5], pk[6], pk[7]);
}

// ---------------------------------------------------------------------------
// Kernel 2: gather + mask overwrite. Grid-stride, one float4 per work item.
// 128 consecutive threads share one (b,s) -> packed word is ~wave-uniform;
// mask branch skipped for ~96% of positions.
// SINGLE CHANGE vs R3 (51.4 us): regular through-L2 store instead of
// nontemporal (R5 vs R7 showed nt costs ~9 us on the block-local body;
// testing the same flip on this grid-stride body).
// ---------------------------------------------------------------------------
__global__ __launch_bounds__(256) void vm_gather_kernel(
    const f32x4* __restrict__ emb,
    const unsigned int* __restrict__ ws,
    f32x4* __restrict__ out)
{
    const int total = Bb * Ss * (DM / 4);    // 16,777,216
    const int stride = gridDim.x * blockDim.x;
    for (int w = blockIdx.x * blockDim.x + threadIdx.x; w < total; w += stride) {
        int bs = w >> 7;                     // 128 quads per (b,s)
        int dq = w & 127;
        unsigned int pw = ws[bs];
        int tk = (int)(pw & 511u);
        f32x4 v = emb[tk * (DM / 4) + dq];
        unsigned int flags = pw >> 9;
        if (flags) {                         // ~wave-uniform branch
            bool valid = (flags & 1u) != 0u;
            bool memf  = (flags & 2u) != 0u;
            int addr = (int)(flags >> 2);
            int p0 = ADDR_KEY      + (addr & 15);
            int p1 = ADDR_KEY + 16 + ((addr >> 4) & 15);
            int p2 = ADDR_KEY + 32 + ((addr >> 8) & 15);
            int d0 = dq << 2;
            #pragma unroll
            for (int j = 0; j < 4; ++j) {
                int d = d0 + j;
                if ((valid && (d == p0 || d == p1 || d == p2)) ||
                    (memf && d == MEM_STORE)) v[j] = 1.0f;
            }
        }
        out[w] = v;                          // regular through-L2 store
    }
}

extern "C" void kernel_launch(void* const* d_in, const int* in_sizes, int n_in,
                              void* d_out, int out_size, void* d_ws, size_t ws_size,
                              hipStream_t stream) {
    const int* tok = (const int*)d_in[0];
    const float* emb = (const float*)d_in[1];
    const int* mhe = (const int*)d_in[2];
    unsigned int* ws = (unsigned int*)d_ws;   // needs Bb*Ss*4 = 512 KiB
    f32x4* out = (f32x4*)d_out;

    vm_scan_kernel<<<Bb, 1024, 0, stream>>>(tok, mhe, ws);
    vm_gather_kernel<<<2048, 256, 0, stream>>>((const f32x4*)emb, ws, out);
}